// Round 8
// baseline (156.354 us; speedup 1.0000x reference)
//
#include <hip/hip_runtime.h>
#include <hip/hip_bf16.h>

#define BATCH 8
#define CIN 256
#define CD 128
#define NPIX 4096  // 64*64

typedef __attribute__((ext_vector_type(2))) float f32x2;
typedef __attribute__((ext_vector_type(4))) float f32x4;
typedef __attribute__((ext_vector_type(16))) float f32x16;
typedef __attribute__((ext_vector_type(8))) short s16x8;
typedef __attribute__((ext_vector_type(4))) short s16x4;
typedef __attribute__((ext_vector_type(2))) unsigned u32x2;

__device__ __forceinline__ short f2bf(float f) {
  union { float f; unsigned u; } v; v.f = f;
  unsigned r = v.u + 0x7fffu + ((v.u >> 16) & 1u);
  return (short)(r >> 16);
}
__device__ __forceinline__ float bf2f(short s) {
  union { unsigned u; float f; } v; v.u = ((unsigned)(unsigned short)s) << 16;
  return v.f;
}
__device__ __forceinline__ float asf(unsigned u) {
  union { unsigned u; float f; } v; v.u = u; return v.f;
}
__device__ __forceinline__ unsigned asu(float f) {
  union { float f; unsigned u; } v; v.f = f; return v.u;
}
// v_cvt_pk_bf16_f32: d = {bf16(a) lo16, bf16(b) hi16}  (T12 recipe)
__device__ __forceinline__ unsigned pkbf(float a, float b) {
  unsigned r;
  asm("v_cvt_pk_bf16_f32 %0, %1, %2" : "=v"(r) : "v"(a), "v"(b));
  return r;
}

#define MFMA(a, b, c) __builtin_amdgcn_mfma_f32_16x16x32_bf16((a), (b), (c), 0, 0, 0)
#define MFMA32(a, b, c) __builtin_amdgcn_mfma_f32_32x32x16_bf16((a), (b), (c), 0, 0, 0)

// async global->LDS, 16B per lane; lds dest = wave-uniform base + lane*16
__device__ __forceinline__ void g2l16(const short* g, short* l) {
  __builtin_amdgcn_global_load_lds(
      (const __attribute__((address_space(1))) void*)g,
      (__attribute__((address_space(3))) void*)l, 16, 0, 0);
}

// ---------------------------------------------------------------- kernel 0
__global__ void k_wconv(const float* __restrict__ Wq, const float* __restrict__ Wk,
                        const float* __restrict__ Wv, const float* __restrict__ Wt,
                        const float* __restrict__ Wf, short* __restrict__ out) {
  int idx = blockIdx.x * 256 + threadIdx.x;  // 0..163839
  int region = idx >> 15;
  const float* src = (region == 0) ? Wq : (region == 1) ? Wk : (region == 2) ? Wv
                     : (region == 3) ? Wt : Wf;
  out[idx] = f2bf(src[idx & 32767]);
}

// ---------------------------------------------------------------- kernel 1
// QKVT projection (unchanged — near its HBM floor)
__global__ __launch_bounds__(512) void k_qkvt(
    const float* __restrict__ ft, const float* __restrict__ fi,
    const short* __restrict__ Wb,
    const float* __restrict__ bq, const float* __restrict__ bk,
    const float* __restrict__ bvp, const float* __restrict__ bt,
    short* __restrict__ Qb, short* __restrict__ Kb,
    short* __restrict__ Vb, short* __restrict__ Tb) {
  __shared__ short lt[64 * 256];
  __shared__ short li[64 * 256];

  int tid = threadIdx.x;
  int b = blockIdx.x >> 6, nt = blockIdx.x & 63;
  int n0 = nt * 64;

#pragma unroll
  for (int t = 0; t < 2; ++t) {
    const float* src = (t == 0 ? ft : fi) + (size_t)b * CIN * NPIX + n0;
    short* dst = (t == 0) ? lt : li;
#pragma unroll
    for (int it = 0; it < 8; ++it) {
      int id = it * 512 + tid;
      int n = id & 63, cg = id >> 6;
      int c0 = cg * 4;
      float x0 = src[(size_t)(c0 + 0) * NPIX + n];
      float x1 = src[(size_t)(c0 + 1) * NPIX + n];
      float x2 = src[(size_t)(c0 + 2) * NPIX + n];
      float x3 = src[(size_t)(c0 + 3) * NPIX + n];
      s16x4 v;
      v.x = f2bf(x0); v.y = f2bf(x1); v.z = f2bf(x2); v.w = f2bf(x3);
      int di = n * 256 + ((((c0 >> 3) ^ (n & 7)) << 3)) + (c0 & 7);
      *(s16x4*)&dst[di] = v;
    }
  }
  __syncthreads();

  int w = tid >> 6, lane = tid & 63;
  int lr = lane & 15, hg = lane >> 4;
  int op = w >> 1, half = w & 1;

  const short* X = (op == 1 || op == 2) ? li : lt;
  const short* W = Wb + op * (CD * CIN);

  f32x4 acc[4][4] = {};

  if (op != 2) {
#pragma unroll
    for (int ks = 0; ks < 8; ++ks) {
      s16x8 a[4];
#pragma unroll
      for (int ni = 0; ni < 4; ++ni) {
        int row = ni * 16 + lr;
        int di = row * 256 + (((ks * 4 + hg) ^ (row & 7)) << 3);
        a[ni] = *(const s16x8*)&X[di];
      }
#pragma unroll
      for (int cj = 0; cj < 4; ++cj) {
        int cd = half * 64 + cj * 16 + lr;
        s16x8 bfr = *(const s16x8*)&W[cd * CIN + ks * 32 + hg * 8];
#pragma unroll
        for (int ni = 0; ni < 4; ++ni) acc[ni][cj] = MFMA(a[ni], bfr, acc[ni][cj]);
      }
    }
    const float* bias = (op == 0) ? bq : (op == 1) ? bk : bt;
    short* out = (op == 0) ? Qb : (op == 1) ? Kb : Tb;
    float scl = (op == 0) ? 0.08838834764831843f : 1.0f;
#pragma unroll
    for (int cj = 0; cj < 4; ++cj) {
      int cd = half * 64 + cj * 16 + lr;
      float bb = bias[cd];
#pragma unroll
      for (int ni = 0; ni < 4; ++ni)
#pragma unroll
        for (int r = 0; r < 4; ++r) {
          int row = n0 + ni * 16 + hg * 4 + r;
          out[((size_t)b * NPIX + row) * CD + cd] = f2bf((acc[ni][cj][r] + bb) * scl);
        }
    }
  } else {
#pragma unroll
    for (int ks = 0; ks < 8; ++ks) {
      s16x8 bx[4];
#pragma unroll
      for (int nj = 0; nj < 4; ++nj) {
        int row = nj * 16 + lr;
        int di = row * 256 + (((ks * 4 + hg) ^ (row & 7)) << 3);
        bx[nj] = *(const s16x8*)&X[di];
      }
#pragma unroll
      for (int ci = 0; ci < 4; ++ci) {
        int cd = half * 64 + ci * 16 + lr;
        s16x8 aw = *(const s16x8*)&W[cd * CIN + ks * 32 + hg * 8];
#pragma unroll
        for (int nj = 0; nj < 4; ++nj) acc[ci][nj] = MFMA(aw, bx[nj], acc[ci][nj]);
      }
    }
#pragma unroll
    for (int ci = 0; ci < 4; ++ci)
#pragma unroll
      for (int r = 0; r < 4; ++r) {
        int cd = half * 64 + ci * 16 + hg * 4 + r;
        float bb = bvp[cd];
#pragma unroll
        for (int nj = 0; nj < 4; ++nj) {
          int col = n0 + nj * 16 + lr;
          Vb[((size_t)b * CD + cd) * NPIX + col] = f2bf(acc[ci][nj][r] + bb);
        }
      }
  }
}

// ---------------------------------------------------------------- kernel 2
// Flash attention v7: 32x32 swapped-operand, KV-split x2, counted-vmcnt
// 2-barrier schedule (T3/T4): staging loads stay in flight across barriers
// (no vmcnt(0) drain in the main loop). max3-friendly row-max tree.
__global__ __launch_bounds__(256, 2) void k_attn(
    const short* __restrict__ Qb, const short* __restrict__ Kb,
    const short* __restrict__ Vb, float* __restrict__ Op,
    float* __restrict__ Lm) {
  __shared__ short Kl[2][64 * 128];   // [m][d], xor-swizzled, 2 x 16 KB
  __shared__ short Vl[2][128 * 64];   // [d][m], xor-swizzled, 2 x 16 KB

  int tid = threadIdx.x;
  int b = blockIdx.x & 7, s = (blockIdx.x >> 3) & 1, qt = blockIdx.x >> 4;
  int q0 = qt * 128;
  int w = tid >> 6, lane = tid & 63;
  int l31 = lane & 31, h = lane >> 5;

  // staging coords: linear LDS granule G holds global granule with swizzled col
  int km[4], kc[4], vd[4], vc[4];
#pragma unroll
  for (int it = 0; it < 4; ++it) {
    int G = it * 256 + tid;
    int m = G >> 4, gi = G & 15;
    km[it] = m; kc[it] = (gi ^ (m & 7)) * 8;
    int d = G >> 3, g2 = G & 7;
    vd[it] = d; vc[it] = (g2 ^ (d & 7)) * 8;
  }
  int ldsb = (tid & ~63) * 8;  // wave-uniform granule base (shorts)

  const short* Kbb = Kb + (size_t)b * NPIX * CD;
  const short* Vbb = Vb + (size_t)b * CD * NPIX;
  int mbase = s * 2048;  // this block's KV half

  // Q fragments: lane holds Q[q = q0+w*32+l31][d = ks*16 + h*8 .. +8]
  s16x8 qf[8];
  const short* qrow = &Qb[((size_t)b * NPIX + q0 + w * 32 + l31) * CD];
#pragma unroll
  for (int ks = 0; ks < 8; ++ks) qf[ks] = *(const s16x8*)&qrow[ks * 16 + h * 8];

  f32x16 o[4] = {};            // O^T: d = dc*32 + (r&3)+8*(r>>2)+4h, q = l31
  float mi = 0.0f, li = 0.0f;  // scalars: one q-row per lane
  const float c2 = 1.4426950408889634f;

  // prologue: stage tile 0 into buf 0 (no drain; loop's first wait covers it)
#pragma unroll
  for (int it = 0; it < 4; ++it) {
    g2l16(&Kbb[(size_t)(mbase + km[it]) * CD + kc[it]], &Kl[0][it * 2048 + ldsb]);
    g2l16(&Vbb[(size_t)vd[it] * NPIX + mbase + vc[it]], &Vl[0][it * 2048 + ldsb]);
  }

  for (int mt = 0; mt < 32; ++mt) {
    int cur = mt & 1;
    // ---- issue next tile, then wait only for the PREVIOUS tile's 8 loads:
    //      the 8 just-issued stay in flight across the barrier (T4).
    if (mt < 31) {
      int m1 = mbase + (mt + 1) * 64;
#pragma unroll
      for (int it = 0; it < 4; ++it) {
        g2l16(&Kbb[(size_t)(m1 + km[it]) * CD + kc[it]], &Kl[cur ^ 1][it * 2048 + ldsb]);
        g2l16(&Vbb[(size_t)vd[it] * NPIX + m1 + vc[it]], &Vl[cur ^ 1][it * 2048 + ldsb]);
      }
      asm volatile("s_waitcnt vmcnt(8)" ::: "memory");
    } else {
      asm volatile("s_waitcnt vmcnt(0)" ::: "memory");
    }
    __builtin_amdgcn_s_barrier();        // all waves' tile-mt loads complete
    __builtin_amdgcn_sched_barrier(0);

    // ---- S^T = K . Q^T, both 32-row halves (sp0: m<32, sp1: m>=32)
    f32x16 sp0 = {}, sp1 = {};
    __builtin_amdgcn_s_setprio(1);
#pragma unroll
    for (int ks = 0; ks < 8; ++ks) {
      int g = (ks * 2 + h) * 8;
      s16x8 ka0 = *(const s16x8*)&Kl[cur][(l31 * 128 + g) ^ ((l31 & 7) << 3)];
      s16x8 ka1 = *(const s16x8*)&Kl[cur][((32 + l31) * 128 + g) ^ ((l31 & 7) << 3)];
      sp0 = MFMA32(ka0, qf[ks], sp0);
      sp1 = MFMA32(ka1, qf[ks], sp1);
    }
    __builtin_amdgcn_s_setprio(0);

    // ---- combined row max (max3-shaped tree) + one permlane
    float t8[8];
#pragma unroll
    for (int i = 0; i < 8; ++i)
      t8[i] = fmaxf(fmaxf(fmaxf(sp0[i], sp0[i + 8]), sp1[i]), sp1[i + 8]);
    float ta = fmaxf(fmaxf(t8[0], t8[1]), t8[2]);
    float tb = fmaxf(fmaxf(t8[3], t8[4]), t8[5]);
    float tc = fmaxf(t8[6], t8[7]);
    float t1 = fmaxf(fmaxf(ta, tb), tc);
    u32x2 mr = __builtin_amdgcn_permlane32_swap(asu(t1), asu(t1), false, false);
    float mx = fmaxf(asf(mr.x), asf(mr.y));
    if (__any(mx > mi + 8.0f)) {  // cold path (defer-max, THR=8)
      float mnew = fmaxf(mi, mx);
      float resc = __builtin_amdgcn_exp2f((mi - mnew) * c2);
      mi = mnew;
      li *= resc;
#pragma unroll
      for (int dc = 0; dc < 4; ++dc)
#pragma unroll
        for (int r = 0; r < 16; ++r) o[dc][r] *= resc;
    }

    // ---- exp both halves
    float mic2 = mi * c2;
#pragma unroll
    for (int r = 0; r < 16; ++r) {
      sp0[r] = __builtin_amdgcn_exp2f(sp0[r] * c2 - mic2);
      sp1[r] = __builtin_amdgcn_exp2f(sp1[r] * c2 - mic2);
    }

    // ---- row sum (both halves) + one permlane
    float s8[8];
#pragma unroll
    for (int i = 0; i < 8; ++i)
      s8[i] = (sp0[i] + sp0[i + 8]) + (sp1[i] + sp1[i + 8]);
#pragma unroll
    for (int i = 0; i < 4; ++i) s8[i] += s8[i + 4];
    float s1 = (s8[0] + s8[1]) + (s8[2] + s8[3]);
    u32x2 sr = __builtin_amdgcn_permlane32_swap(asu(s1), asu(s1), false, false);
    li += asf(sr.x) + asf(sr.y);

    // ---- repack P -> bf16 B-frags via cvt_pk + permlane32_swap
    s16x8 pb[4];
#pragma unroll
    for (int hf = 0; hf < 2; ++hf)
#pragma unroll
      for (int t = 0; t < 2; ++t) {
        const f32x16& sp = hf ? sp1 : sp0;
        unsigned lo0 = pkbf(sp[8 * t + 0], sp[8 * t + 1]);
        unsigned hi0 = pkbf(sp[8 * t + 2], sp[8 * t + 3]);
        unsigned lo1 = pkbf(sp[8 * t + 4], sp[8 * t + 5]);
        unsigned hi1 = pkbf(sp[8 * t + 6], sp[8 * t + 7]);
        u32x2 rl = __builtin_amdgcn_permlane32_swap(lo0, lo1, false, false);
        u32x2 rh = __builtin_amdgcn_permlane32_swap(hi0, hi1, false, false);
        union { unsigned u[4]; s16x8 v; } pu;
        pu.u[0] = rl.x; pu.u[1] = rh.x; pu.u[2] = rl.y; pu.u[3] = rh.y;
        pb[hf * 2 + t] = pu.v;
      }

    // ---- O^T += V^T . P^T
    __builtin_amdgcn_s_setprio(1);
#pragma unroll
    for (int ms = 0; ms < 4; ++ms) {
      int g = (ms * 2 + h) * 8;
#pragma unroll
      for (int dc = 0; dc < 4; ++dc) {
        int d = dc * 32 + l31;
        s16x8 av = *(const s16x8*)&Vl[cur][(d * 64 + g) ^ ((d & 7) << 3)];
        o[dc] = MFMA32(av, pb[ms], o[dc]);
      }
    }
    __builtin_amdgcn_s_setprio(0);

    // ---- read-complete barrier (no vmcnt drain: 8 loads stay in flight)
    asm volatile("s_waitcnt lgkmcnt(0)" ::: "memory");
    __builtin_amdgcn_sched_barrier(0);
    __builtin_amdgcn_s_barrier();
    __builtin_amdgcn_sched_barrier(0);
  }

  // ---- epilogue: write unnormalized partial O (f32) + (li, mi)
  int q = q0 + w * 32 + l31;
  size_t rowOff = ((size_t)(s * 8 + b) * NPIX + q) * CD;
#pragma unroll
  for (int dc = 0; dc < 4; ++dc)
#pragma unroll
    for (int rr = 0; rr < 4; ++rr) {
      f32x4 v;
      v.x = o[dc][rr * 4 + 0]; v.y = o[dc][rr * 4 + 1];
      v.z = o[dc][rr * 4 + 2]; v.w = o[dc][rr * 4 + 3];
      *(f32x4*)&Op[rowOff + dc * 32 + rr * 8 + h * 4] = v;
    }
  if (h == 0) {
    f32x2 lm; lm.x = li; lm.y = mi;
    *(f32x2*)&Lm[((size_t)(s * 8 + b) * NPIX + q) * 2] = lm;
  }
}

// ---------------------------------------------------------------- kernel 2b
// (fallback path) Combine KV-split halves + tproj -> fusedX bf16
__global__ __launch_bounds__(256) void k_comb(
    const float* __restrict__ Op, const float* __restrict__ Lm,
    const short* __restrict__ Tb, short* __restrict__ Xb) {
  int idx = blockIdx.x * 256 + threadIdx.x;  // 524288 = 8*4096*16
  int dq = idx & 15;
  int q = (idx >> 4) & 4095;
  int b = idx >> 16;
  const float c2 = 1.4426950408889634f;

  size_t r1 = (size_t)b * NPIX + q;
  size_t r2 = (size_t)(8 + b) * NPIX + q;
  f32x2 lm1 = *(const f32x2*)&Lm[r1 * 2];
  f32x2 lm2 = *(const f32x2*)&Lm[r2 * 2];
  float m = fmaxf(lm1.y, lm2.y);
  float w1 = __builtin_amdgcn_exp2f((lm1.y - m) * c2);
  float w2 = __builtin_amdgcn_exp2f((lm2.y - m) * c2);
  float inv = 1.0f / (lm1.x * w1 + lm2.x * w2);
  w1 *= inv; w2 *= inv;

  f32x4 o1a = *(const f32x4*)&Op[r1 * CD + dq * 8];
  f32x4 o1b = *(const f32x4*)&Op[r1 * CD + dq * 8 + 4];
  f32x4 o2a = *(const f32x4*)&Op[r2 * CD + dq * 8];
  f32x4 o2b = *(const f32x4*)&Op[r2 * CD + dq * 8 + 4];
  s16x8 tp = *(const s16x8*)&Tb[r1 * CD + dq * 8];
  union { unsigned u[4]; s16x8 v; } xv;
  xv.u[0] = pkbf(o1a.x * w1 + o2a.x * w2 + bf2f(tp[0]),
                 o1a.y * w1 + o2a.y * w2 + bf2f(tp[1]));
  xv.u[1] = pkbf(o1a.z * w1 + o2a.z * w2 + bf2f(tp[2]),
                 o1a.w * w1 + o2a.w * w2 + bf2f(tp[3]));
  xv.u[2] = pkbf(o1b.x * w1 + o2b.x * w2 + bf2f(tp[4]),
                 o1b.y * w1 + o2b.y * w2 + bf2f(tp[5]));
  xv.u[3] = pkbf(o1b.z * w1 + o2b.z * w2 + bf2f(tp[6]),
                 o1b.w * w1 + o2b.w * w2 + bf2f(tp[7]));
  *(s16x8*)&Xb[r1 * CD + dq * 8] = xv.v;
}

// ---------------------------------------------------------------- kernel 3
// (fallback path) out = Wf . Xb + bf
__global__ __launch_bounds__(256) void k_out(
    const short* __restrict__ Wfb, const float* __restrict__ bfp,
    const short* __restrict__ Xb, float* __restrict__ out) {
  int tid = threadIdx.x;
  int b = blockIdx.x >> 6, nt = blockIdx.x & 63, n0 = nt * 64;
  int w = tid >> 6, lane = tid & 63, lr = lane & 15, hg = lane >> 4;

  f32x4 acc[4][4] = {};
#pragma unroll
  for (int ks = 0; ks < 4; ++ks) {
    s16x8 af[4], bx[4];
#pragma unroll
    for (int os = 0; os < 4; ++os)
      af[os] = *(const s16x8*)&Wfb[(w * 64 + os * 16 + lr) * CD + ks * 32 + hg * 8];
#pragma unroll
    for (int nc = 0; nc < 4; ++nc)
      bx[nc] = *(const s16x8*)&Xb[((size_t)b * NPIX + n0 + nc * 16 + lr) * CD + ks * 32 + hg * 8];
#pragma unroll
    for (int os = 0; os < 4; ++os)
#pragma unroll
      for (int nc = 0; nc < 4; ++nc) acc[os][nc] = MFMA(af[os], bx[nc], acc[os][nc]);
  }
#pragma unroll
  for (int os = 0; os < 4; ++os)
#pragma unroll
    for (int r = 0; r < 4; ++r) {
      int oc = w * 64 + os * 16 + hg * 4 + r;
      float bias = bfp[oc];
#pragma unroll
      for (int nc = 0; nc < 4; ++nc) {
        int n = n0 + nc * 16 + lr;
        out[((size_t)b * CIN + oc) * NPIX + n] = acc[os][nc][r] + bias;
      }
    }
}

// ---------------------------------------------------------------- kernel 3f
// Fused combine + out: out = Wf . (combine(Op1,Op2,Lm) + tproj) + bf.
// Same pkbf rounding point as k_comb -> identical numerics.
__global__ __launch_bounds__(256) void k_outf(
    const short* __restrict__ Wfb, const float* __restrict__ bfp,
    const float* __restrict__ Op, const float* __restrict__ Lm,
    const short* __restrict__ Tb, float* __restrict__ out) {
  int tid = threadIdx.x;
  int b = blockIdx.x >> 6, nt = blockIdx.x & 63, n0 = nt * 64;
  int w = tid >> 6, lane = tid & 63, lr = lane & 15, hg = lane >> 4;
  const float c2 = 1.4426950408889634f;

  // per-lane combine weights for rows n = n0 + nc*16 + lr
  float w1[4], w2[4];
  size_t r1b[4], r2b[4];
#pragma unroll
  for (int nc = 0; nc < 4; ++nc) {
    int n = n0 + nc * 16 + lr;
    size_t r1 = (size_t)b * NPIX + n;
    size_t r2 = (size_t)(8 + b) * NPIX + n;
    r1b[nc] = r1 * CD; r2b[nc] = r2 * CD;
    f32x2 lm1 = *(const f32x2*)&Lm[r1 * 2];
    f32x2 lm2 = *(const f32x2*)&Lm[r2 * 2];
    float m = fmaxf(lm1.y, lm2.y);
    float a1 = __builtin_amdgcn_exp2f((lm1.y - m) * c2);
    float a2 = __builtin_amdgcn_exp2f((lm2.y - m) * c2);
    float inv = 1.0f / (lm1.x * a1 + lm2.x * a2);
    w1[nc] = a1 * inv; w2[nc] = a2 * inv;
  }

  f32x4 acc[4][4] = {};
#pragma unroll
  for (int ks = 0; ks < 4; ++ks) {
    s16x8 af[4], bx[4];
#pragma unroll
    for (int os = 0; os < 4; ++os)
      af[os] = *(const s16x8*)&Wfb[(w * 64 + os * 16 + lr) * CD + ks * 32 + hg * 8];
#pragma unroll
    for (int nc = 0; nc < 4; ++nc) {
      int d0 = ks * 32 + hg * 8;
      f32x4 o1a = *(const f32x4*)&Op[r1b[nc] + d0];
      f32x4 o1b = *(const f32x4*)&Op[r1b[nc] + d0 + 4];
      f32x4 o2a = *(const f32x4*)&Op[r2b[nc] + d0];
      f32x4 o2b = *(const f32x4*)&Op[r2b[nc] + d0 + 4];
      s16x8 tp = *(const s16x8*)&Tb[r1b[nc] + d0];
      union { unsigned u[4]; s16x8 v; } xv;
      xv.u[0] = pkbf(o1a.x * w1[nc] + o2a.x * w2[nc] + bf2f(tp[0]),
                     o1a.y * w1[nc] + o2a.y * w2[nc] + bf2f(tp[1]));
      xv.u[1] = pkbf(o1a.z * w1[nc] + o2a.z * w2[nc] + bf2f(tp[2]),
                     o1a.w * w1[nc] + o2a.w * w2[nc] + bf2f(tp[3]));
      xv.u[2] = pkbf(o1b.x * w1[nc] + o2b.x * w2[nc] + bf2f(tp[4]),
                     o1b.y * w1[nc] + o2b.y * w2[nc] + bf2f(tp[5]));
      xv.u[3] = pkbf(o1b.z * w1[nc] + o2b.z * w2[nc] + bf2f(tp[6]),
                     o1b.w * w1[nc] + o2b.w * w2[nc] + bf2f(tp[7]));
      bx[nc] = xv.v;
    }
#pragma unroll
    for (int os = 0; os < 4; ++os)
#pragma unroll
      for (int nc = 0; nc < 4; ++nc) acc[os][nc] = MFMA(af[os], bx[nc], acc[os][nc]);
  }
#pragma unroll
  for (int os = 0; os < 4; ++os)
#pragma unroll
    for (int r = 0; r < 4; ++r) {
      int oc = w * 64 + os * 16 + hg * 4 + r;
      float bias = bfp[oc];
#pragma unroll
      for (int nc = 0; nc < 4; ++nc) {
        int n = n0 + nc * 16 + lr;
        out[((size_t)b * CIN + oc) * NPIX + n] = acc[os][nc][r] + bias;
      }
    }
}

// ---------------------------------------------------------------- launch
extern "C" void kernel_launch(void* const* d_in, const int* in_sizes, int n_in,
                              void* d_out, int out_size, void* d_ws, size_t ws_size,
                              hipStream_t stream) {
  const float* ft = (const float*)d_in[0];
  const float* fi = (const float*)d_in[1];
  const float* Wq = (const float*)d_in[2];
  const float* bq = (const float*)d_in[3];
  const float* Wk = (const float*)d_in[4];
  const float* bk = (const float*)d_in[5];
  const float* Wv = (const float*)d_in[6];
  const float* bv = (const float*)d_in[7];
  const float* Wt = (const float*)d_in[8];
  const float* bt = (const float*)d_in[9];
  const float* Wf = (const float*)d_in[10];
  const float* bf = (const float*)d_in[11];
  float* out = (float*)d_out;

  short* wsS = (short*)d_ws;
  short* Qb = wsS;
  short* Kb = wsS + 4194304;
  short* Vb = wsS + 8388608;
  short* Tb = wsS + 12582912;
  short* Xb = wsS + 16777216;
  short* Wb = wsS + 20971520;              // 163840 shorts of bf16 weights
  float* Lm = (float*)(wsS + 21135360);    // 2*8*4096*2 floats = 1 MB (ends 21,397,504 shorts)
  float* OpW = (float*)(wsS + 21397504);   // optional 33.5 MB partial-O in ws

  // fused path needs ws up to 76,349,440 bytes; otherwise use d_out as scratch
  bool fused = ws_size >= (size_t)76349440;
  float* Op = fused ? OpW : out;

  k_wconv<<<640, 256, 0, stream>>>(Wq, Wk, Wv, Wt, Wf, Wb);
  k_qkvt<<<512, 512, 0, stream>>>(ft, fi, Wb, bq, bk, bv, bt, Qb, Kb, Vb, Tb);
  k_attn<<<512, 256, 0, stream>>>(Qb, Kb, Vb, Op, Lm);
  if (fused) {
    k_outf<<<512, 256, 0, stream>>>(Wb + 4 * CD * CIN, bf, Op, Lm, Tb, out);
  } else {
    k_comb<<<2048, 256, 0, stream>>>(Op, Lm, Tb, Xb);
    k_out<<<512, 256, 0, stream>>>(Wb + 4 * CD * CIN, bf, Xb, out);
  }
}

// Round 9
// 141.262 us; speedup vs baseline: 1.1068x; 1.1068x over previous
//
#include <hip/hip_runtime.h>
#include <hip/hip_bf16.h>

#define BATCH 8
#define CIN 256
#define CD 128
#define NPIX 4096  // 64*64

typedef __attribute__((ext_vector_type(2))) float f32x2;
typedef __attribute__((ext_vector_type(4))) float f32x4;
typedef __attribute__((ext_vector_type(16))) float f32x16;
typedef __attribute__((ext_vector_type(8))) short s16x8;
typedef __attribute__((ext_vector_type(4))) short s16x4;
typedef __attribute__((ext_vector_type(2))) unsigned u32x2;

__device__ __forceinline__ short f2bf(float f) {
  union { float f; unsigned u; } v; v.f = f;
  unsigned r = v.u + 0x7fffu + ((v.u >> 16) & 1u);
  return (short)(r >> 16);
}
__device__ __forceinline__ float bf2f(short s) {
  union { unsigned u; float f; } v; v.u = ((unsigned)(unsigned short)s) << 16;
  return v.f;
}
__device__ __forceinline__ float asf(unsigned u) {
  union { unsigned u; float f; } v; v.u = u; return v.f;
}
__device__ __forceinline__ unsigned asu(float f) {
  union { float f; unsigned u; } v; v.f = f; return v.u;
}
// v_cvt_pk_bf16_f32: d = {bf16(a) lo16, bf16(b) hi16}  (T12 recipe)
__device__ __forceinline__ unsigned pkbf(float a, float b) {
  unsigned r;
  asm("v_cvt_pk_bf16_f32 %0, %1, %2" : "=v"(r) : "v"(a), "v"(b));
  return r;
}

#define MFMA(a, b, c) __builtin_amdgcn_mfma_f32_16x16x32_bf16((a), (b), (c), 0, 0, 0)
#define MFMA32(a, b, c) __builtin_amdgcn_mfma_f32_32x32x16_bf16((a), (b), (c), 0, 0, 0)

// async global->LDS, 16B per lane; lds dest = wave-uniform base + lane*16
__device__ __forceinline__ void g2l16(const short* g, short* l) {
  __builtin_amdgcn_global_load_lds(
      (const __attribute__((address_space(1))) void*)g,
      (__attribute__((address_space(3))) void*)l, 16, 0, 0);
}

// ---------------------------------------------------------------- kernel 0
__global__ void k_wconv(const float* __restrict__ Wq, const float* __restrict__ Wk,
                        const float* __restrict__ Wv, const float* __restrict__ Wt,
                        const float* __restrict__ Wf, short* __restrict__ out) {
  int idx = blockIdx.x * 256 + threadIdx.x;  // 0..163839
  int region = idx >> 15;
  const float* src = (region == 0) ? Wq : (region == 1) ? Wk : (region == 2) ? Wv
                     : (region == 3) ? Wt : Wf;
  out[idx] = f2bf(src[idx & 32767]);
}

// ---------------------------------------------------------------- kernel 1
// QKVT projection (unchanged — near its HBM floor)
__global__ __launch_bounds__(512) void k_qkvt(
    const float* __restrict__ ft, const float* __restrict__ fi,
    const short* __restrict__ Wb,
    const float* __restrict__ bq, const float* __restrict__ bk,
    const float* __restrict__ bvp, const float* __restrict__ bt,
    short* __restrict__ Qb, short* __restrict__ Kb,
    short* __restrict__ Vb, short* __restrict__ Tb) {
  __shared__ short lt[64 * 256];
  __shared__ short li[64 * 256];

  int tid = threadIdx.x;
  int b = blockIdx.x >> 6, nt = blockIdx.x & 63;
  int n0 = nt * 64;

#pragma unroll
  for (int t = 0; t < 2; ++t) {
    const float* src = (t == 0 ? ft : fi) + (size_t)b * CIN * NPIX + n0;
    short* dst = (t == 0) ? lt : li;
#pragma unroll
    for (int it = 0; it < 8; ++it) {
      int id = it * 512 + tid;
      int n = id & 63, cg = id >> 6;
      int c0 = cg * 4;
      float x0 = src[(size_t)(c0 + 0) * NPIX + n];
      float x1 = src[(size_t)(c0 + 1) * NPIX + n];
      float x2 = src[(size_t)(c0 + 2) * NPIX + n];
      float x3 = src[(size_t)(c0 + 3) * NPIX + n];
      s16x4 v;
      v.x = f2bf(x0); v.y = f2bf(x1); v.z = f2bf(x2); v.w = f2bf(x3);
      int di = n * 256 + ((((c0 >> 3) ^ (n & 7)) << 3)) + (c0 & 7);
      *(s16x4*)&dst[di] = v;
    }
  }
  __syncthreads();

  int w = tid >> 6, lane = tid & 63;
  int lr = lane & 15, hg = lane >> 4;
  int op = w >> 1, half = w & 1;

  const short* X = (op == 1 || op == 2) ? li : lt;
  const short* W = Wb + op * (CD * CIN);

  f32x4 acc[4][4] = {};

  if (op != 2) {
#pragma unroll
    for (int ks = 0; ks < 8; ++ks) {
      s16x8 a[4];
#pragma unroll
      for (int ni = 0; ni < 4; ++ni) {
        int row = ni * 16 + lr;
        int di = row * 256 + (((ks * 4 + hg) ^ (row & 7)) << 3);
        a[ni] = *(const s16x8*)&X[di];
      }
#pragma unroll
      for (int cj = 0; cj < 4; ++cj) {
        int cd = half * 64 + cj * 16 + lr;
        s16x8 bfr = *(const s16x8*)&W[cd * CIN + ks * 32 + hg * 8];
#pragma unroll
        for (int ni = 0; ni < 4; ++ni) acc[ni][cj] = MFMA(a[ni], bfr, acc[ni][cj]);
      }
    }
    const float* bias = (op == 0) ? bq : (op == 1) ? bk : bt;
    short* out = (op == 0) ? Qb : (op == 1) ? Kb : Tb;
    float scl = (op == 0) ? 0.08838834764831843f : 1.0f;
#pragma unroll
    for (int cj = 0; cj < 4; ++cj) {
      int cd = half * 64 + cj * 16 + lr;
      float bb = bias[cd];
#pragma unroll
      for (int ni = 0; ni < 4; ++ni)
#pragma unroll
        for (int r = 0; r < 4; ++r) {
          int row = n0 + ni * 16 + hg * 4 + r;
          out[((size_t)b * NPIX + row) * CD + cd] = f2bf((acc[ni][cj][r] + bb) * scl);
        }
    }
  } else {
#pragma unroll
    for (int ks = 0; ks < 8; ++ks) {
      s16x8 bx[4];
#pragma unroll
      for (int nj = 0; nj < 4; ++nj) {
        int row = nj * 16 + lr;
        int di = row * 256 + (((ks * 4 + hg) ^ (row & 7)) << 3);
        bx[nj] = *(const s16x8*)&X[di];
      }
#pragma unroll
      for (int ci = 0; ci < 4; ++ci) {
        int cd = half * 64 + ci * 16 + lr;
        s16x8 aw = *(const s16x8*)&W[cd * CIN + ks * 32 + hg * 8];
#pragma unroll
        for (int nj = 0; nj < 4; ++nj) acc[ci][nj] = MFMA(aw, bx[nj], acc[ci][nj]);
      }
    }
#pragma unroll
    for (int ci = 0; ci < 4; ++ci)
#pragma unroll
      for (int r = 0; r < 4; ++r) {
        int cd = half * 64 + ci * 16 + hg * 4 + r;
        float bb = bvp[cd];
#pragma unroll
        for (int nj = 0; nj < 4; ++nj) {
          int col = n0 + nj * 16 + lr;
          Vb[((size_t)b * CD + cd) * NPIX + col] = f2bf(acc[ci][nj][r] + bb);
        }
      }
  }
}

// ---------------------------------------------------------------- kernel 2
// Flash attention v8: in-block KV-split. 512 thr = 8 waves: waves 0-3 do KV
// rows [0,2048), waves 4-7 do [2048,4096), same 128 q-rows. Grid 256 =
// 1 block/CU (bid&7 = batch -> XCD L2 affinity), 2 waves/SIMD. Main loop =
// v7 (counted-vmcnt 2-barrier). Combine is a 64KB LDS round-trip in the
// epilogue (replaces k_comb's ~100MB global traffic); fused tproj add.
__global__ __launch_bounds__(512, 2) void k_attn(
    const short* __restrict__ Qb, const short* __restrict__ Kb,
    const short* __restrict__ Vb, const short* __restrict__ Tb,
    short* __restrict__ Xb) {
  __shared__ short Kl[32768];   // [grp][buf][64*128] xor-swizzled, 64 KB
  __shared__ short Vl[32768];   // [grp][buf][128*64] xor-swizzled, 64 KB

  int tid = threadIdx.x;
  int b = blockIdx.x & 7, qt = blockIdx.x >> 3;
  int q0 = qt * 128;
  int w = tid >> 6, lane = tid & 63;
  int l31 = lane & 31, h = lane >> 5;
  int wg = w & 3, grp = w >> 2;   // grp = KV half
  int gtid = tid & 255;           // thread id within group
  int GB = grp * 16384;           // group LDS base (shorts)

  // staging coords: linear LDS granule G holds global granule with swizzled col
  int km[4], kc[4], vd[4], vc[4];
#pragma unroll
  for (int it = 0; it < 4; ++it) {
    int G = it * 256 + gtid;
    int m = G >> 4, gi = G & 15;
    km[it] = m; kc[it] = (gi ^ (m & 7)) * 8;
    int d = G >> 3, g2 = G & 7;
    vd[it] = d; vc[it] = (g2 ^ (d & 7)) * 8;
  }
  int ldsb = (gtid & ~63) * 8;  // wave-uniform granule base within group buf

  const short* Kbb = Kb + (size_t)b * NPIX * CD;
  const short* Vbb = Vb + (size_t)b * CD * NPIX;
  int mbase = grp * 2048;

  // Q fragments: lane holds Q[q][d = ks*16 + h*8 .. +8]
  int q = q0 + wg * 32 + l31;
  s16x8 qf[8];
  const short* qrow = &Qb[((size_t)b * NPIX + q) * CD];
#pragma unroll
  for (int ks = 0; ks < 8; ++ks) qf[ks] = *(const s16x8*)&qrow[ks * 16 + h * 8];

  f32x16 o[4] = {};            // O^T: d = dc*32 + (r&3)+8*(r>>2)+4h, q = l31
  float mi = 0.0f, li = 0.0f;
  const float c2 = 1.4426950408889634f;

  // prologue: stage tile 0 into buf 0
#pragma unroll
  for (int it = 0; it < 4; ++it) {
    g2l16(&Kbb[(size_t)(mbase + km[it]) * CD + kc[it]], &Kl[GB + it * 2048 + ldsb]);
    g2l16(&Vbb[(size_t)vd[it] * NPIX + mbase + vc[it]], &Vl[GB + it * 2048 + ldsb]);
  }

  for (int mt = 0; mt < 32; ++mt) {
    int cur = mt & 1;
    if (mt < 31) {
      int m1 = mbase + (mt + 1) * 64;
#pragma unroll
      for (int it = 0; it < 4; ++it) {
        g2l16(&Kbb[(size_t)(m1 + km[it]) * CD + kc[it]],
              &Kl[GB + (cur ^ 1) * 8192 + it * 2048 + ldsb]);
        g2l16(&Vbb[(size_t)vd[it] * NPIX + m1 + vc[it]],
              &Vl[GB + (cur ^ 1) * 8192 + it * 2048 + ldsb]);
      }
      asm volatile("s_waitcnt vmcnt(8)" ::: "memory");
    } else {
      asm volatile("s_waitcnt vmcnt(0)" ::: "memory");
    }
    __builtin_amdgcn_s_barrier();
    __builtin_amdgcn_sched_barrier(0);

    const short* Kc = &Kl[GB + cur * 8192];
    const short* Vc = &Vl[GB + cur * 8192];

    // ---- S^T = K . Q^T, both 32-row halves (sp0: m<32, sp1: m>=32)
    f32x16 sp0 = {}, sp1 = {};
    __builtin_amdgcn_s_setprio(1);
#pragma unroll
    for (int ks = 0; ks < 8; ++ks) {
      int gc = (ks * 2 + h) * 8;
      s16x8 ka0 = *(const s16x8*)&Kc[(l31 * 128 + gc) ^ ((l31 & 7) << 3)];
      s16x8 ka1 = *(const s16x8*)&Kc[((32 + l31) * 128 + gc) ^ ((l31 & 7) << 3)];
      sp0 = MFMA32(ka0, qf[ks], sp0);
      sp1 = MFMA32(ka1, qf[ks], sp1);
    }
    __builtin_amdgcn_s_setprio(0);

    // ---- combined row max (max3-shaped tree) + one permlane
    float t8[8];
#pragma unroll
    for (int i = 0; i < 8; ++i)
      t8[i] = fmaxf(fmaxf(fmaxf(sp0[i], sp0[i + 8]), sp1[i]), sp1[i + 8]);
    float ta = fmaxf(fmaxf(t8[0], t8[1]), t8[2]);
    float tb = fmaxf(fmaxf(t8[3], t8[4]), t8[5]);
    float tc = fmaxf(t8[6], t8[7]);
    float t1 = fmaxf(fmaxf(ta, tb), tc);
    u32x2 mr = __builtin_amdgcn_permlane32_swap(asu(t1), asu(t1), false, false);
    float mx = fmaxf(asf(mr.x), asf(mr.y));
    if (__any(mx > mi + 8.0f)) {  // cold path (defer-max, THR=8)
      float mnew = fmaxf(mi, mx);
      float resc = __builtin_amdgcn_exp2f((mi - mnew) * c2);
      mi = mnew;
      li *= resc;
#pragma unroll
      for (int dc = 0; dc < 4; ++dc)
#pragma unroll
        for (int r = 0; r < 16; ++r) o[dc][r] *= resc;
    }

    // ---- exp both halves
    float mic2 = mi * c2;
#pragma unroll
    for (int r = 0; r < 16; ++r) {
      sp0[r] = __builtin_amdgcn_exp2f(sp0[r] * c2 - mic2);
      sp1[r] = __builtin_amdgcn_exp2f(sp1[r] * c2 - mic2);
    }

    // ---- row sum (both halves) + one permlane
    float s8[8];
#pragma unroll
    for (int i = 0; i < 8; ++i)
      s8[i] = (sp0[i] + sp0[i + 8]) + (sp1[i] + sp1[i + 8]);
#pragma unroll
    for (int i = 0; i < 4; ++i) s8[i] += s8[i + 4];
    float s1 = (s8[0] + s8[1]) + (s8[2] + s8[3]);
    u32x2 sr = __builtin_amdgcn_permlane32_swap(asu(s1), asu(s1), false, false);
    li += asf(sr.x) + asf(sr.y);

    // ---- repack P -> bf16 B-frags via cvt_pk + permlane32_swap
    s16x8 pb[4];
#pragma unroll
    for (int hf = 0; hf < 2; ++hf)
#pragma unroll
      for (int t = 0; t < 2; ++t) {
        const f32x16& sp = hf ? sp1 : sp0;
        unsigned lo0 = pkbf(sp[8 * t + 0], sp[8 * t + 1]);
        unsigned hi0 = pkbf(sp[8 * t + 2], sp[8 * t + 3]);
        unsigned lo1 = pkbf(sp[8 * t + 4], sp[8 * t + 5]);
        unsigned hi1 = pkbf(sp[8 * t + 6], sp[8 * t + 7]);
        u32x2 rl = __builtin_amdgcn_permlane32_swap(lo0, lo1, false, false);
        u32x2 rh = __builtin_amdgcn_permlane32_swap(hi0, hi1, false, false);
        union { unsigned u[4]; s16x8 v; } pu;
        pu.u[0] = rl.x; pu.u[1] = rh.x; pu.u[2] = rl.y; pu.u[3] = rh.y;
        pb[hf * 2 + t] = pu.v;
      }

    // ---- O^T += V^T . P^T
    __builtin_amdgcn_s_setprio(1);
#pragma unroll
    for (int ms = 0; ms < 4; ++ms) {
      int gc = (ms * 2 + h) * 8;
#pragma unroll
      for (int dc = 0; dc < 4; ++dc) {
        int d = dc * 32 + l31;
        s16x8 av = *(const s16x8*)&Vc[(d * 64 + gc) ^ ((d & 7) << 3)];
        o[dc] = MFMA32(av, pb[ms], o[dc]);
      }
    }
    __builtin_amdgcn_s_setprio(0);

    // ---- read-complete barrier (no vmcnt drain: 8 loads stay in flight)
    asm volatile("s_waitcnt lgkmcnt(0)" ::: "memory");
    __builtin_amdgcn_sched_barrier(0);
    __builtin_amdgcn_s_barrier();
    __builtin_amdgcn_sched_barrier(0);
  }

  // ---- epilogue: in-block combine via LDS (reuses dead K/V regions).
  // Group 0 publishes unnormalized O (f32, swizzled quads) + (li,mi);
  // group 1 reconciles, adds tproj, writes Xb bf16.
  float* Ol = (float*)Kl;    // 64 KB: quad addr (row*32 + dcs)*4 floats
  float* lml = (float*)Vl;   // 1 KB: [row][2] = (li, mi)
  int row = wg * 32 + l31;
  if (w < 4) {
#pragma unroll
    for (int dc = 0; dc < 4; ++dc)
#pragma unroll
      for (int rr = 0; rr < 4; ++rr) {
        int dci = dc * 8 + rr * 2 + h;
        int dcs = dci ^ ((row & 7) << 2);
        f32x4 v;
        v.x = o[dc][rr * 4 + 0]; v.y = o[dc][rr * 4 + 1];
        v.z = o[dc][rr * 4 + 2]; v.w = o[dc][rr * 4 + 3];
        *(f32x4*)&Ol[(row * 32 + dcs) * 4] = v;
      }
    if (h == 0) { lml[row * 2] = li; lml[row * 2 + 1] = mi; }
  }
  __syncthreads();
  if (w >= 4) {
    float l0 = lml[row * 2], m0 = lml[row * 2 + 1];
    float m = fmaxf(m0, mi);
    float w0 = __builtin_amdgcn_exp2f((m0 - m) * c2);
    float w1 = __builtin_amdgcn_exp2f((mi - m) * c2);
    float inv = 1.0f / (l0 * w0 + li * w1);
    w0 *= inv; w1 *= inv;
    size_t rowOff = ((size_t)b * NPIX + q) * CD;
#pragma unroll
    for (int dc = 0; dc < 4; ++dc)
#pragma unroll
      for (int rr = 0; rr < 4; ++rr) {
        int dci = dc * 8 + rr * 2 + h;
        int dcs = dci ^ ((row & 7) << 2);
        f32x4 o0 = *(const f32x4*)&Ol[(row * 32 + dcs) * 4];
        int d = dc * 32 + rr * 8 + h * 4;
        size_t off = rowOff + d;
        s16x4 tp = *(const s16x4*)&Tb[off];
        float f0 = o0.x * w0 + o[dc][rr * 4 + 0] * w1 + bf2f(tp.x);
        float f1 = o0.y * w0 + o[dc][rr * 4 + 1] * w1 + bf2f(tp.y);
        float f2 = o0.z * w0 + o[dc][rr * 4 + 2] * w1 + bf2f(tp.z);
        float f3 = o0.w * w0 + o[dc][rr * 4 + 3] * w1 + bf2f(tp.w);
        union { unsigned u[2]; s16x4 v; } xv;
        xv.u[0] = pkbf(f0, f1); xv.u[1] = pkbf(f2, f3);
        *(s16x4*)&Xb[off] = xv.v;
      }
  }
}

// ---------------------------------------------------------------- kernel 3
// out = Wf . Xb + bf   (fp32 out, coalesced 64B stores)
__global__ __launch_bounds__(256) void k_out(
    const short* __restrict__ Wfb, const float* __restrict__ bfp,
    const short* __restrict__ Xb, float* __restrict__ out) {
  int tid = threadIdx.x;
  int b = blockIdx.x >> 6, nt = blockIdx.x & 63, n0 = nt * 64;
  int w = tid >> 6, lane = tid & 63, lr = lane & 15, hg = lane >> 4;

  f32x4 acc[4][4] = {};
#pragma unroll
  for (int ks = 0; ks < 4; ++ks) {
    s16x8 af[4], bx[4];
#pragma unroll
    for (int os = 0; os < 4; ++os)
      af[os] = *(const s16x8*)&Wfb[(w * 64 + os * 16 + lr) * CD + ks * 32 + hg * 8];
#pragma unroll
    for (int nc = 0; nc < 4; ++nc)
      bx[nc] = *(const s16x8*)&Xb[((size_t)b * NPIX + n0 + nc * 16 + lr) * CD + ks * 32 + hg * 8];
#pragma unroll
    for (int os = 0; os < 4; ++os)
#pragma unroll
      for (int nc = 0; nc < 4; ++nc) acc[os][nc] = MFMA(af[os], bx[nc], acc[os][nc]);
  }
#pragma unroll
  for (int os = 0; os < 4; ++os)
#pragma unroll
    for (int r = 0; r < 4; ++r) {
      int oc = w * 64 + os * 16 + hg * 4 + r;
      float bias = bfp[oc];
#pragma unroll
      for (int nc = 0; nc < 4; ++nc) {
        int n = n0 + nc * 16 + lr;
        out[((size_t)b * CIN + oc) * NPIX + n] = acc[os][nc][r] + bias;
      }
    }
}

// ---------------------------------------------------------------- launch
extern "C" void kernel_launch(void* const* d_in, const int* in_sizes, int n_in,
                              void* d_out, int out_size, void* d_ws, size_t ws_size,
                              hipStream_t stream) {
  const float* ft = (const float*)d_in[0];
  const float* fi = (const float*)d_in[1];
  const float* Wq = (const float*)d_in[2];
  const float* bq = (const float*)d_in[3];
  const float* Wk = (const float*)d_in[4];
  const float* bk = (const float*)d_in[5];
  const float* Wv = (const float*)d_in[6];
  const float* bv = (const float*)d_in[7];
  const float* Wt = (const float*)d_in[8];
  const float* bt = (const float*)d_in[9];
  const float* Wf = (const float*)d_in[10];
  const float* bf = (const float*)d_in[11];
  float* out = (float*)d_out;

  short* wsS = (short*)d_ws;
  short* Qb = wsS;
  short* Kb = wsS + 4194304;
  short* Vb = wsS + 8388608;
  short* Tb = wsS + 12582912;
  short* Xb = wsS + 16777216;
  short* Wb = wsS + 20971520;   // 163840 shorts of bf16 weights (~42.3 MB total)

  k_wconv<<<640, 256, 0, stream>>>(Wq, Wk, Wv, Wt, Wf, Wb);
  k_qkvt<<<512, 512, 0, stream>>>(ft, fi, Wb, bq, bk, bv, bt, Qb, Kb, Vb, Tb);
  k_attn<<<256, 512, 0, stream>>>(Qb, Kb, Vb, Tb, Xb);
  k_out<<<512, 256, 0, stream>>>(Wb + 4 * CD * CIN, bf, Xb, out);
}